// Round 3
// baseline (1183.952 us; speedup 1.0000x reference)
//
#include <hip/hip_runtime.h>

// Problem dims (fixed by init_kwargs)
#define N_TOK 2048   // B*T
#define DIM   512    // D
#define HID   2048   // H
#define NG    4
#define NE    8
#define NP    32     // NG*NE
#define EPS   1e-5f

// ---- workspace layout (bytes). Total ~84.2 MiB ----
static constexpr size_t OFF_Z    = 0;                                        // z: [N,D] f32
static constexpr size_t OFF_H    = OFF_Z    + (size_t)N_TOK*DIM*4;           // hbuf: [8192,H] f32
static constexpr size_t OFF_EO   = OFF_H    + (size_t)N_TOK*4*HID*4;         // eout: [8192,D] f32
static constexpr size_t OFF_LIST = OFF_EO   + (size_t)N_TOK*4*DIM*4;         // list: [8192] i32
static constexpr size_t OFF_SLOT = OFF_LIST + (size_t)N_TOK*4*4;             // slotof: [N,4] i32
static constexpr size_t OFF_SELG = OFF_SLOT + (size_t)N_TOK*4*4;             // selg: [N,2] i32
static constexpr size_t OFF_GWS  = OFF_SELG + (size_t)N_TOK*2*4;             // gws:  [N,2] f32
static constexpr size_t OFF_SELE = OFF_GWS  + (size_t)N_TOK*2*4;             // sele: [N,4] i32
static constexpr size_t OFF_EW   = OFF_SELE + (size_t)N_TOK*4*4;             // ew:   [N,4] f32
static constexpr size_t OFF_CNT  = OFF_EW   + (size_t)N_TOK*4*4;             // counts[32]
static constexpr size_t OFF_OFFS = OFF_CNT  + 128;                           // offs[32]
static constexpr size_t OFF_CUR  = OFF_OFFS + 128;                           // cursors[32]

// ---------------- K1: group gate + outer LN + inner gate, per token ----------------
__global__ __launch_bounds__(256) void k_gate_ln(
    const float* __restrict__ inp, const float* __restrict__ ln_g, const float* __restrict__ ln_b,
    const float* __restrict__ wgg, const float* __restrict__ wgi,
    float* __restrict__ z, int* __restrict__ selg, float* __restrict__ gws,
    int* __restrict__ sele, float* __restrict__ ew, int* __restrict__ counts)
{
    const int n = blockIdx.x;
    const int t = threadIdx.x;
    __shared__ float red[256];
    __shared__ float zsh[DIM];
    __shared__ float lg[NG];
    __shared__ float il[NP];
    __shared__ float part[NP][8];

    const float x0 = inp[n*DIM + t];
    const float x1 = inp[n*DIM + t + 256];

    // mean
    red[t] = x0 + x1; __syncthreads();
    for (int s = 128; s > 0; s >>= 1) { if (t < s) red[t] += red[t+s]; __syncthreads(); }
    const float mean = red[0] * (1.0f/DIM);
    __syncthreads();
    // var (biased, matches reference)
    red[t] = (x0-mean)*(x0-mean) + (x1-mean)*(x1-mean); __syncthreads();
    for (int s = 128; s > 0; s >>= 1) { if (t < s) red[t] += red[t+s]; __syncthreads(); }
    const float rstd = rsqrtf(red[0]*(1.0f/DIM) + EPS);
    __syncthreads();

    const float z0 = (x0-mean)*rstd*ln_g[t]     + ln_b[t];
    const float z1 = (x1-mean)*rstd*ln_g[t+256] + ln_b[t+256];
    z[n*DIM + t]       = z0;
    z[n*DIM + t + 256] = z1;
    zsh[t] = z0; zsh[t+256] = z1;
    __syncthreads();

    // group logits on RAW x: 4 block reductions
    for (int g = 0; g < NG; ++g) {
        red[t] = x0*wgg[t*NG + g] + x1*wgg[(t+256)*NG + g];
        __syncthreads();
        for (int s = 128; s > 0; s >>= 1) { if (t < s) red[t] += red[t+s]; __syncthreads(); }
        if (t == 0) lg[g] = red[0];
        __syncthreads();
    }

    // inner logits on z: thread t -> pair p=t&31, d-slice (t>>5)::8
    {
        const int p = t & 31, g = p >> 3, e = p & 7, ds = t >> 5;
        float acc = 0.f;
        for (int d = ds; d < DIM; d += 8)
            acc += zsh[d] * wgi[(g*DIM + d)*NE + e];
        part[p][ds] = acc;
    }
    __syncthreads();
    if (t < NP) {
        float s = 0.f;
        #pragma unroll
        for (int q = 0; q < 8; ++q) s += part[t][q];
        il[t] = s;
    }
    __syncthreads();

    if (t == 0) {
        // top-2 of 4 groups (ties -> lowest index, matches lax.top_k)
        int i1 = 0;
        for (int g = 1; g < NG; ++g) if (lg[g] > lg[i1]) i1 = g;
        int i2 = -1;
        for (int g = 0; g < NG; ++g) { if (g == i1) continue; if (i2 < 0 || lg[g] > lg[i2]) i2 = g; }
        const float e2 = expf(lg[i2] - lg[i1]);
        gws[n*2+0] = 1.f/(1.f+e2);
        gws[n*2+1] = e2/(1.f+e2);
        selg[n*2+0] = i1; selg[n*2+1] = i2;
        for (int s = 0; s < 2; ++s) {
            const int g = (s == 0) ? i1 : i2;
            const float* l = &il[g*NE];
            int j1 = 0;
            for (int e = 1; e < NE; ++e) if (l[e] > l[j1]) j1 = e;
            int j2 = -1;
            for (int e = 0; e < NE; ++e) { if (e == j1) continue; if (j2 < 0 || l[e] > l[j2]) j2 = e; }
            const float f2 = expf(l[j2] - l[j1]);
            sele[n*4+s*2+0] = j1; sele[n*4+s*2+1] = j2;
            ew[n*4+s*2+0] = 1.f/(1.f+f2);
            ew[n*4+s*2+1] = f2/(1.f+f2);
            atomicAdd(&counts[g*NE + j1], 1);
            atomicAdd(&counts[g*NE + j2], 1);
        }
    }
}

// ---------------- K2: exclusive prefix over 32 pair counts ----------------
__global__ void k_prefix(const int* __restrict__ counts, int* __restrict__ offs,
                         int* __restrict__ cursors)
{
    if (threadIdx.x == 0) {
        int acc = 0;
        for (int p = 0; p < NP; ++p) { offs[p] = acc; acc += counts[p]; }
    }
    if (threadIdx.x < NP) cursors[threadIdx.x] = 0;
}

// ---------------- K3: fill per-pair token lists ----------------
__global__ void k_route(const int* __restrict__ selg, const int* __restrict__ sele,
                        int* __restrict__ cursors, const int* __restrict__ offs,
                        int* __restrict__ list, int* __restrict__ slotof)
{
    const int n = blockIdx.x*blockDim.x + threadIdx.x;
    if (n >= N_TOK) return;
    for (int s = 0; s < 2; ++s) {
        const int g = selg[n*2+s];
        for (int q = 0; q < 2; ++q) {
            const int e = sele[n*4+s*2+q];
            const int p = g*NE + e;
            const int pos = atomicAdd(&cursors[p], 1);
            const int slot = offs[p] + pos;
            list[slot] = n;
            slotof[n*4+s*2+q] = slot;
        }
    }
}

// ---------------- K4: grouped GEMM  h = relu(z[list] @ W1[p] + b1[p]) ----------------
// tile 128x128, BK=16, 256 threads, 8x8 micro-tile
__global__ __launch_bounds__(256) void k_ffn1(
    const float* __restrict__ z, const float* __restrict__ W1, const float* __restrict__ b1,
    const int* __restrict__ counts, const int* __restrict__ offs, const int* __restrict__ list,
    float* __restrict__ hbuf)
{
    const int p = blockIdx.z;
    const int cnt = counts[p];
    const int row0 = blockIdx.y * 128;
    if (row0 >= cnt) return;
    const int col0 = blockIdx.x * 128;
    const int base = offs[p];
    const float* __restrict__ Wp = W1 + (size_t)p * DIM * HID;   // [D][H] row-major

    __shared__ float As[16][128];
    __shared__ float Bs[16][132];

    const int tid  = threadIdx.x;
    const int arow = tid >> 1;            // 0..127
    const int akp  = (tid & 1) * 8;       // 0 or 8
    const int brow = tid >> 4;            // 0..15
    const int bcol = (tid & 15) * 8;      // 0..120
    const int ty = tid >> 4, tx = tid & 15;

    int an = -1;
    if (row0 + arow < cnt) an = list[base + row0 + arow];

    float acc[8][8] = {};

    for (int kk = 0; kk < DIM; kk += 16) {
        if (an >= 0) {
            const float* src = z + (size_t)an*DIM + kk + akp;
            #pragma unroll
            for (int j = 0; j < 8; ++j) As[akp+j][arow] = src[j];
        } else {
            #pragma unroll
            for (int j = 0; j < 8; ++j) As[akp+j][arow] = 0.f;
        }
        {
            const float* src = Wp + (size_t)(kk + brow)*HID + col0 + bcol;
            #pragma unroll
            for (int j = 0; j < 8; ++j) Bs[brow][bcol+j] = src[j];
        }
        __syncthreads();
        #pragma unroll
        for (int k = 0; k < 16; ++k) {
            float a[8], b[8];
            #pragma unroll
            for (int i = 0; i < 8; ++i) a[i] = As[k][ty*8+i];
            #pragma unroll
            for (int j = 0; j < 8; ++j) b[j] = Bs[k][tx*8+j];
            #pragma unroll
            for (int i = 0; i < 8; ++i)
                #pragma unroll
                for (int j = 0; j < 8; ++j)
                    acc[i][j] += a[i]*b[j];
        }
        __syncthreads();
    }

    const float* bb = b1 + (size_t)p*HID + col0 + tx*8;
    #pragma unroll
    for (int i = 0; i < 8; ++i) {
        const int r = row0 + ty*8 + i;
        if (r >= cnt) break;
        float* dst = hbuf + (size_t)(base + r)*HID + col0 + tx*8;
        #pragma unroll
        for (int j = 0; j < 8; ++j) {
            const float v = acc[i][j] + bb[j];
            dst[j] = v > 0.f ? v : 0.f;
        }
    }
}

// ---------------- K5: grouped GEMM  eout = hbuf @ W2[p] + b2[p] ----------------
__global__ __launch_bounds__(256) void k_ffn2(
    const float* __restrict__ hbuf, const float* __restrict__ W2, const float* __restrict__ b2,
    const int* __restrict__ counts, const int* __restrict__ offs,
    float* __restrict__ eout)
{
    const int p = blockIdx.z;
    const int cnt = counts[p];
    const int row0 = blockIdx.y * 128;
    if (row0 >= cnt) return;
    const int col0 = blockIdx.x * 128;
    const int base = offs[p];
    const float* __restrict__ Wp = W2 + (size_t)p * HID * DIM;   // [H][D]

    __shared__ float As[16][128];
    __shared__ float Bs[16][132];

    const int tid  = threadIdx.x;
    const int arow = tid >> 1;
    const int akp  = (tid & 1) * 8;
    const int brow = tid >> 4;
    const int bcol = (tid & 15) * 8;
    const int ty = tid >> 4, tx = tid & 15;

    const bool avalid = (row0 + arow < cnt);

    float acc[8][8] = {};

    for (int kk = 0; kk < HID; kk += 16) {
        if (avalid) {
            const float* src = hbuf + (size_t)(base + row0 + arow)*HID + kk + akp;
            #pragma unroll
            for (int j = 0; j < 8; ++j) As[akp+j][arow] = src[j];
        } else {
            #pragma unroll
            for (int j = 0; j < 8; ++j) As[akp+j][arow] = 0.f;
        }
        {
            const float* src = Wp + (size_t)(kk + brow)*DIM + col0 + bcol;
            #pragma unroll
            for (int j = 0; j < 8; ++j) Bs[brow][bcol+j] = src[j];
        }
        __syncthreads();
        #pragma unroll
        for (int k = 0; k < 16; ++k) {
            float a[8], b[8];
            #pragma unroll
            for (int i = 0; i < 8; ++i) a[i] = As[k][ty*8+i];
            #pragma unroll
            for (int j = 0; j < 8; ++j) b[j] = Bs[k][tx*8+j];
            #pragma unroll
            for (int i = 0; i < 8; ++i)
                #pragma unroll
                for (int j = 0; j < 8; ++j)
                    acc[i][j] += a[i]*b[j];
        }
        __syncthreads();
    }

    const float* bb = b2 + (size_t)p*DIM + col0 + tx*8;
    #pragma unroll
    for (int i = 0; i < 8; ++i) {
        const int r = row0 + ty*8 + i;
        if (r >= cnt) break;
        float* dst = eout + (size_t)(base + r)*DIM + col0 + tx*8;
        #pragma unroll
        for (int j = 0; j < 8; ++j) dst[j] = acc[i][j] + bb[j];
    }
}

// ---------------- K7: combine experts, group LN, gate-weighted sum, residual ----------------
__global__ __launch_bounds__(256) void k_final(
    const float* __restrict__ inp, const float* __restrict__ z,
    const float* __restrict__ eout, const int* __restrict__ selg, const float* __restrict__ gws,
    const float* __restrict__ ew, const int* __restrict__ slotof,
    const float* __restrict__ glng, const float* __restrict__ glnb,
    float* __restrict__ out)
{
    const int n = blockIdx.x;
    const int t = threadIdx.x;
    __shared__ float red[256];

    const float z0 = z[n*DIM + t],      z1 = z[n*DIM + t + 256];
    float o0 = inp[n*DIM + t],          o1 = inp[n*DIM + t + 256];

    for (int s = 0; s < 2; ++s) {
        const int g = selg[n*2+s];
        const float wgr = gws[n*2+s];
        const int   sl0 = slotof[n*4+s*2+0], sl1 = slotof[n*4+s*2+1];
        const float w0  = ew[n*4+s*2+0],     w1 = ew[n*4+s*2+1];

        const float u0 = z0 + w0*eout[(size_t)sl0*DIM + t]      + w1*eout[(size_t)sl1*DIM + t];
        const float u1 = z1 + w0*eout[(size_t)sl0*DIM + t + 256] + w1*eout[(size_t)sl1*DIM + t + 256];

        red[t] = u0 + u1; __syncthreads();
        for (int ss = 128; ss > 0; ss >>= 1) { if (t < ss) red[t] += red[t+ss]; __syncthreads(); }
        const float m = red[0]*(1.0f/DIM);
        __syncthreads();
        red[t] = (u0-m)*(u0-m) + (u1-m)*(u1-m); __syncthreads();
        for (int ss = 128; ss > 0; ss >>= 1) { if (t < ss) red[t] += red[t+ss]; __syncthreads(); }
        const float rstd = rsqrtf(red[0]*(1.0f/DIM) + EPS);
        __syncthreads();

        o0 += wgr * ((u0-m)*rstd*glng[g*DIM + t]       + glnb[g*DIM + t]);
        o1 += wgr * ((u1-m)*rstd*glng[g*DIM + t + 256] + glnb[g*DIM + t + 256]);
    }
    out[n*DIM + t]       = o0;
    out[n*DIM + t + 256] = o1;
}

extern "C" void kernel_launch(void* const* d_in, const int* in_sizes, int n_in,
                              void* d_out, int out_size, void* d_ws, size_t ws_size,
                              hipStream_t stream)
{
    const float* inp  = (const float*)d_in[0];
    const float* ln_g = (const float*)d_in[1];
    const float* ln_b = (const float*)d_in[2];
    const float* wgg  = (const float*)d_in[3];
    const float* wgi  = (const float*)d_in[4];
    const float* W1   = (const float*)d_in[5];
    const float* b1   = (const float*)d_in[6];
    const float* W2   = (const float*)d_in[7];
    const float* b2   = (const float*)d_in[8];
    const float* glng = (const float*)d_in[9];
    const float* glnb = (const float*)d_in[10];
    float* out = (float*)d_out;

    char* ws = (char*)d_ws;
    float* z      = (float*)(ws + OFF_Z);
    float* hbuf   = (float*)(ws + OFF_H);
    float* eout   = (float*)(ws + OFF_EO);
    int*   list   = (int*)  (ws + OFF_LIST);
    int*   slotof = (int*)  (ws + OFF_SLOT);
    int*   selg   = (int*)  (ws + OFF_SELG);
    float* gws    = (float*)(ws + OFF_GWS);
    int*   sele   = (int*)  (ws + OFF_SELE);
    float* ew     = (float*)(ws + OFF_EW);
    int*   counts = (int*)  (ws + OFF_CNT);
    int*   offs   = (int*)  (ws + OFF_OFFS);
    int*   curs   = (int*)  (ws + OFF_CUR);

    hipMemsetAsync(ws + OFF_CNT, 0, 384, stream);
    k_gate_ln<<<N_TOK, 256, 0, stream>>>(inp, ln_g, ln_b, wgg, wgi, z, selg, gws, sele, ew, counts);
    k_prefix<<<1, 64, 0, stream>>>(counts, offs, curs);
    k_route<<<N_TOK/256, 256, 0, stream>>>(selg, sele, curs, offs, list, slotof);
    k_ffn1<<<dim3(HID/128, N_TOK/128, NP), 256, 0, stream>>>(z, W1, b1, counts, offs, list, hbuf);
    k_ffn2<<<dim3(DIM/128, N_TOK/128, NP), 256, 0, stream>>>(hbuf, W2, b2, counts, offs, eout);
    k_final<<<N_TOK, 256, 0, stream>>>(inp, z, eout, selg, gws, ew, slotof, glng, glnb, out);
}

// Round 4
// 565.195 us; speedup vs baseline: 2.0948x; 2.0948x over previous
//
#include <hip/hip_runtime.h>

// Problem dims (fixed)
#define N_TOK 2048   // B*T
#define DIM   512    // D
#define HID   2048   // H
#define NG    4
#define NE    8
#define NP    32
#define NROUTE (N_TOK*4)   // 8192 routed (token,expert) slots
#define EPS   1e-5f

typedef __attribute__((ext_vector_type(8))) short short8;
typedef __attribute__((ext_vector_type(4))) float f32x4;
typedef unsigned short u16;
typedef unsigned int   u32;

__device__ __forceinline__ u16 f2bf(float f) {
    u32 u = __float_as_uint(f);
    u32 r = u + 0x7fffu + ((u >> 16) & 1u);   // RNE
    return (u16)(r >> 16);
}
__device__ __forceinline__ float bf2f(u16 h) {
    return __uint_as_float(((u32)h) << 16);
}

// ---- workspace layout (bytes). Total ~118.2 MiB ----
static constexpr size_t OFF_Z    = 0;                          // z f32 [N][D]       4 MiB
static constexpr size_t OFF_ZB   = 4u  * 1024 * 1024;          // z bf16 [N][D]      2 MiB
static constexpr size_t OFF_WT   = 6u  * 1024 * 1024;          // Wt bf16 (shared W1T/W2T) 64 MiB
static constexpr size_t OFF_H    = 70u * 1024 * 1024;          // hbuf bf16 [8192][H] 32 MiB
static constexpr size_t OFF_EO   = 102u* 1024 * 1024;          // eout bf16 [2][8192][D] 16 MiB
static constexpr size_t OFF_LIST = 118u* 1024 * 1024;          // list [8192] i32
static constexpr size_t OFF_SLOT = OFF_LIST + NROUTE*4;        // slotof [N][4] i32
static constexpr size_t OFF_SELG = OFF_SLOT + (size_t)N_TOK*4*4;
static constexpr size_t OFF_GWS  = OFF_SELG + (size_t)N_TOK*2*4;
static constexpr size_t OFF_SELE = OFF_GWS  + (size_t)N_TOK*2*4;
static constexpr size_t OFF_EW   = OFF_SELE + (size_t)N_TOK*4*4;
static constexpr size_t OFF_CNT  = OFF_EW   + (size_t)N_TOK*4*4;
static constexpr size_t OFF_OFFS = OFF_CNT  + 128;
static constexpr size_t OFF_CUR  = OFF_OFFS + 128;

// ---------------- K1: group gate + outer LN + inner gate, per token ----------------
__global__ __launch_bounds__(256) void k_gate_ln(
    const float* __restrict__ inp, const float* __restrict__ ln_g, const float* __restrict__ ln_b,
    const float* __restrict__ wgg, const float* __restrict__ wgi,
    float* __restrict__ z, u16* __restrict__ zb,
    int* __restrict__ selg, float* __restrict__ gws,
    int* __restrict__ sele, float* __restrict__ ew, int* __restrict__ counts)
{
    const int n = blockIdx.x;
    const int t = threadIdx.x;
    __shared__ float red[256];
    __shared__ float zsh[DIM];
    __shared__ float lg[NG];
    __shared__ float il[NP];
    __shared__ float part[NP][8];

    const float x0 = inp[n*DIM + t];
    const float x1 = inp[n*DIM + t + 256];

    red[t] = x0 + x1; __syncthreads();
    for (int s = 128; s > 0; s >>= 1) { if (t < s) red[t] += red[t+s]; __syncthreads(); }
    const float mean = red[0] * (1.0f/DIM);
    __syncthreads();
    red[t] = (x0-mean)*(x0-mean) + (x1-mean)*(x1-mean); __syncthreads();
    for (int s = 128; s > 0; s >>= 1) { if (t < s) red[t] += red[t+s]; __syncthreads(); }
    const float rstd = rsqrtf(red[0]*(1.0f/DIM) + EPS);
    __syncthreads();

    const float z0 = (x0-mean)*rstd*ln_g[t]     + ln_b[t];
    const float z1 = (x1-mean)*rstd*ln_g[t+256] + ln_b[t+256];
    z[n*DIM + t]        = z0;
    z[n*DIM + t + 256]  = z1;
    zb[n*DIM + t]       = f2bf(z0);
    zb[n*DIM + t + 256] = f2bf(z1);
    zsh[t] = z0; zsh[t+256] = z1;
    __syncthreads();

    for (int g = 0; g < NG; ++g) {
        red[t] = x0*wgg[t*NG + g] + x1*wgg[(t+256)*NG + g];
        __syncthreads();
        for (int s = 128; s > 0; s >>= 1) { if (t < s) red[t] += red[t+s]; __syncthreads(); }
        if (t == 0) lg[g] = red[0];
        __syncthreads();
    }

    {
        const int p = t & 31, g = p >> 3, e = p & 7, ds = t >> 5;
        float acc = 0.f;
        for (int d = ds; d < DIM; d += 8)
            acc += zsh[d] * wgi[(g*DIM + d)*NE + e];
        part[p][ds] = acc;
    }
    __syncthreads();
    if (t < NP) {
        float s = 0.f;
        #pragma unroll
        for (int q = 0; q < 8; ++q) s += part[t][q];
        il[t] = s;
    }
    __syncthreads();

    if (t == 0) {
        int i1 = 0;
        for (int g = 1; g < NG; ++g) if (lg[g] > lg[i1]) i1 = g;
        int i2 = -1;
        for (int g = 0; g < NG; ++g) { if (g == i1) continue; if (i2 < 0 || lg[g] > lg[i2]) i2 = g; }
        const float e2 = expf(lg[i2] - lg[i1]);
        gws[n*2+0] = 1.f/(1.f+e2);
        gws[n*2+1] = e2/(1.f+e2);
        selg[n*2+0] = i1; selg[n*2+1] = i2;
        for (int s = 0; s < 2; ++s) {
            const int g = (s == 0) ? i1 : i2;
            const float* l = &il[g*NE];
            int j1 = 0;
            for (int e = 1; e < NE; ++e) if (l[e] > l[j1]) j1 = e;
            int j2 = -1;
            for (int e = 0; e < NE; ++e) { if (e == j1) continue; if (j2 < 0 || l[e] > l[j2]) j2 = e; }
            const float f2 = expf(l[j2] - l[j1]);
            sele[n*4+s*2+0] = j1; sele[n*4+s*2+1] = j2;
            ew[n*4+s*2+0] = 1.f/(1.f+f2);
            ew[n*4+s*2+1] = f2/(1.f+f2);
            atomicAdd(&counts[g*NE + j1], 1);
            atomicAdd(&counts[g*NE + j2], 1);
        }
    }
}

// ---------------- K2: exclusive prefix over 32 pair counts ----------------
__global__ void k_prefix(const int* __restrict__ counts, int* __restrict__ offs,
                         int* __restrict__ cursors)
{
    if (threadIdx.x == 0) {
        int acc = 0;
        for (int p = 0; p < NP; ++p) { offs[p] = acc; acc += counts[p]; }
    }
    if (threadIdx.x < NP) cursors[threadIdx.x] = 0;
}

// ---------------- K3: fill per-pair token lists ----------------
__global__ void k_route(const int* __restrict__ selg, const int* __restrict__ sele,
                        int* __restrict__ cursors, const int* __restrict__ offs,
                        int* __restrict__ list, int* __restrict__ slotof)
{
    const int n = blockIdx.x*blockDim.x + threadIdx.x;
    if (n >= N_TOK) return;
    for (int s = 0; s < 2; ++s) {
        const int g = selg[n*2+s];
        for (int q = 0; q < 2; ++q) {
            const int e = sele[n*4+s*2+q];
            const int p = g*NE + e;
            const int pos = atomicAdd(&cursors[p], 1);
            const int slot = offs[p] + pos;
            list[slot] = n;
            slotof[n*4+s*2+q] = slot;
        }
    }
}

// ---------------- transpose + f32->bf16 convert:  dst[p][c][r] = src[p][r][c] ----------------
__global__ __launch_bounds__(256) void k_transpose_cvt(
    const float* __restrict__ src, u16* __restrict__ dst, int R, int C)
{
    const int p  = blockIdx.z;
    const int c0 = blockIdx.x * 64;
    const int r0 = blockIdx.y * 64;
    __shared__ float t[64][65];
    const int tid = threadIdx.x;
    const int lr = tid >> 4;            // 0..15
    const int lc = (tid & 15) * 4;      // 0..60
    const float* sp = src + (size_t)p * R * C;
    #pragma unroll
    for (int i = 0; i < 4; ++i) {
        const float4 v = *(const float4*)(sp + (size_t)(r0 + lr + i*16) * C + c0 + lc);
        t[lr + i*16][lc+0] = v.x; t[lr + i*16][lc+1] = v.y;
        t[lr + i*16][lc+2] = v.z; t[lr + i*16][lc+3] = v.w;
    }
    __syncthreads();
    u16* dp = dst + (size_t)p * C * R;
    #pragma unroll
    for (int i = 0; i < 2; ++i) {
        const int chunk = tid + 256*i;       // 0..511
        const int c  = chunk >> 3;           // 0..63
        const int kq = (chunk & 7) * 8;      // 0..56
        u32 w0 = (u32)f2bf(t[kq+0][c]) | ((u32)f2bf(t[kq+1][c]) << 16);
        u32 w1 = (u32)f2bf(t[kq+2][c]) | ((u32)f2bf(t[kq+3][c]) << 16);
        u32 w2 = (u32)f2bf(t[kq+4][c]) | ((u32)f2bf(t[kq+5][c]) << 16);
        u32 w3 = (u32)f2bf(t[kq+6][c]) | ((u32)f2bf(t[kq+7][c]) << 16);
        uint4 u; u.x = w0; u.y = w1; u.z = w2; u.w = w3;
        *(uint4*)(dp + (size_t)(c0 + c) * R + r0 + kq) = u;
    }
}

// ---------------- K4: MFMA grouped GEMM  h = relu(z[list] @ W1[p] + b1[p]) ----------------
// 128x128 tile, BK=64 bf16, 4 waves (2x2), acc 4x4 frags of 16x16x32
__global__ __launch_bounds__(256) void k_ffn1_mfma(
    const u16* __restrict__ zb, const u16* __restrict__ w1t, const float* __restrict__ b1,
    const int* __restrict__ counts, const int* __restrict__ offs, const int* __restrict__ list,
    u16* __restrict__ hbuf)
{
    const int p = blockIdx.z;
    const int cnt = counts[p];
    const int row0 = blockIdx.y * 128;
    if (row0 >= cnt) return;
    const int col0 = blockIdx.x * 128;
    const int base = offs[p];

    __shared__ short8 Al[1024];   // [128 rows][8 16B-chunks], idx ^ (row&7) swizzle
    __shared__ short8 Bl[1024];
    __shared__ int tok[128];

    const int tid = threadIdx.x;
    if (tid < 128) {
        int idx = base + row0 + tid;
        if (idx > NROUTE - 1) idx = NROUTE - 1;
        tok[tid] = list[idx];
    }
    const int l  = tid & 63, w = tid >> 6;
    const int wm = w >> 1, wn = w & 1;
    const int fr = l & 15, fq = l >> 4;

    f32x4 acc[4][4] = {};
    const u16* wp = w1t + (size_t)p * HID * DIM;   // [H][D] bf16

    __syncthreads();

    for (int kk = 0; kk < DIM; kk += 64) {
        #pragma unroll
        for (int i = 0; i < 4; ++i) {
            const int ch = tid + 256*i;
            const int r = ch >> 3, kc = ch & 7;
            Al[(r*8 + kc) ^ (r & 7)] = *(const short8*)(zb + (size_t)tok[r]*DIM + kk + kc*8);
        }
        #pragma unroll
        for (int i = 0; i < 4; ++i) {
            const int ch = tid + 256*i;
            const int c = ch >> 3, kc = ch & 7;
            Bl[(c*8 + kc) ^ (c & 7)] = *(const short8*)(wp + (size_t)(col0 + c)*DIM + kk + kc*8);
        }
        __syncthreads();
        #pragma unroll
        for (int ks = 0; ks < 2; ++ks) {
            short8 a[4], b[4];
            #pragma unroll
            for (int m = 0; m < 4; ++m) {
                const int r = wm*64 + m*16 + fr;
                a[m] = Al[(r*8 + ks*4 + fq) ^ (r & 7)];
            }
            #pragma unroll
            for (int n = 0; n < 4; ++n) {
                const int c = wn*64 + n*16 + fr;
                b[n] = Bl[(c*8 + ks*4 + fq) ^ (c & 7)];
            }
            #pragma unroll
            for (int m = 0; m < 4; ++m)
                #pragma unroll
                for (int n = 0; n < 4; ++n)
                    acc[m][n] = __builtin_amdgcn_mfma_f32_16x16x32_bf16(a[m], b[n], acc[m][n], 0, 0, 0);
        }
        __syncthreads();
    }

    const float* bp = b1 + (size_t)p * HID;
    #pragma unroll
    for (int n = 0; n < 4; ++n) {
        const int col = col0 + wn*64 + n*16 + fr;
        const float bias = bp[col];
        #pragma unroll
        for (int m = 0; m < 4; ++m) {
            #pragma unroll
            for (int j = 0; j < 4; ++j) {
                const int r = row0 + wm*64 + m*16 + fq*4 + j;
                if (r < cnt) {
                    float v = acc[m][n][j] + bias;
                    v = v > 0.f ? v : 0.f;
                    hbuf[(size_t)(base + r)*HID + col] = f2bf(v);
                }
            }
        }
    }
}

// ---------------- K5: MFMA grouped GEMM  eout[half] = hbuf @ W2[p] (K-half) ----------------
__global__ __launch_bounds__(256) void k_ffn2_mfma(
    const u16* __restrict__ hbuf, const u16* __restrict__ w2t,
    const int* __restrict__ counts, const int* __restrict__ offs,
    u16* __restrict__ eout)
{
    const int pz = blockIdx.z;
    const int p = pz >> 1, half = pz & 1;
    const int cnt = counts[p];
    const int row0 = blockIdx.y * 128;
    if (row0 >= cnt) return;
    const int col0 = blockIdx.x * 128;
    const int base = offs[p];
    const int k0 = half * (HID/2);

    __shared__ short8 Al[1024];
    __shared__ short8 Bl[1024];

    const int tid = threadIdx.x;
    const int l  = tid & 63, w = tid >> 6;
    const int wm = w >> 1, wn = w & 1;
    const int fr = l & 15, fq = l >> 4;

    f32x4 acc[4][4] = {};
    const u16* wp = w2t + (size_t)p * DIM * HID;   // [D][H] bf16

    for (int kk = 0; kk < HID/2; kk += 64) {
        #pragma unroll
        for (int i = 0; i < 4; ++i) {
            const int ch = tid + 256*i;
            const int r = ch >> 3, kc = ch & 7;
            int gr = base + row0 + r; if (gr > NROUTE - 1) gr = NROUTE - 1;
            Al[(r*8 + kc) ^ (r & 7)] = *(const short8*)(hbuf + (size_t)gr*HID + k0 + kk + kc*8);
        }
        #pragma unroll
        for (int i = 0; i < 4; ++i) {
            const int ch = tid + 256*i;
            const int c = ch >> 3, kc = ch & 7;
            Bl[(c*8 + kc) ^ (c & 7)] = *(const short8*)(wp + (size_t)(col0 + c)*HID + k0 + kk + kc*8);
        }
        __syncthreads();
        #pragma unroll
        for (int ks = 0; ks < 2; ++ks) {
            short8 a[4], b[4];
            #pragma unroll
            for (int m = 0; m < 4; ++m) {
                const int r = wm*64 + m*16 + fr;
                a[m] = Al[(r*8 + ks*4 + fq) ^ (r & 7)];
            }
            #pragma unroll
            for (int n = 0; n < 4; ++n) {
                const int c = wn*64 + n*16 + fr;
                b[n] = Bl[(c*8 + ks*4 + fq) ^ (c & 7)];
            }
            #pragma unroll
            for (int m = 0; m < 4; ++m)
                #pragma unroll
                for (int n = 0; n < 4; ++n)
                    acc[m][n] = __builtin_amdgcn_mfma_f32_16x16x32_bf16(a[m], b[n], acc[m][n], 0, 0, 0);
        }
        __syncthreads();
    }

    u16* ep = eout + (size_t)half * NROUTE * DIM;
    #pragma unroll
    for (int n = 0; n < 4; ++n) {
        const int col = col0 + wn*64 + n*16 + fr;
        #pragma unroll
        for (int m = 0; m < 4; ++m) {
            #pragma unroll
            for (int j = 0; j < 4; ++j) {
                const int r = row0 + wm*64 + m*16 + fq*4 + j;
                if (r < cnt)
                    ep[(size_t)(base + r)*DIM + col] = f2bf(acc[m][n][j]);
            }
        }
    }
}

// ---------------- K7: combine experts, group LN, gate-weighted sum, residual ----------------
__global__ __launch_bounds__(256) void k_final(
    const float* __restrict__ inp, const float* __restrict__ z,
    const u16* __restrict__ eout, const float* __restrict__ b2,
    const int* __restrict__ selg, const float* __restrict__ gws,
    const float* __restrict__ ew, const int* __restrict__ slotof,
    const float* __restrict__ glng, const float* __restrict__ glnb,
    float* __restrict__ out)
{
    const int n = blockIdx.x;
    const int t = threadIdx.x;
    __shared__ float red[256];
    const u16* eA = eout;
    const u16* eB = eout + (size_t)NROUTE * DIM;

    const float z0 = z[n*DIM + t],      z1 = z[n*DIM + t + 256];
    float o0 = inp[n*DIM + t],          o1 = inp[n*DIM + t + 256];

    for (int s = 0; s < 2; ++s) {
        const int g = selg[n*2+s];
        const float wgr = gws[n*2+s];
        const int   sl0 = slotof[n*4+s*2+0], sl1 = slotof[n*4+s*2+1];
        const float w0  = ew[n*4+s*2+0],     w1 = ew[n*4+s*2+1];

        const float e00 = bf2f(eA[(size_t)sl0*DIM + t])       + bf2f(eB[(size_t)sl0*DIM + t]);
        const float e01 = bf2f(eA[(size_t)sl0*DIM + t + 256]) + bf2f(eB[(size_t)sl0*DIM + t + 256]);
        const float e10 = bf2f(eA[(size_t)sl1*DIM + t])       + bf2f(eB[(size_t)sl1*DIM + t]);
        const float e11 = bf2f(eA[(size_t)sl1*DIM + t + 256]) + bf2f(eB[(size_t)sl1*DIM + t + 256]);

        // top-2 softmax weights sum to 1 => bias b2 contributes exactly once
        const float u0 = z0 + w0*e00 + w1*e10 + b2[g*DIM + t];
        const float u1 = z1 + w0*e01 + w1*e11 + b2[g*DIM + t + 256];

        red[t] = u0 + u1; __syncthreads();
        for (int ss = 128; ss > 0; ss >>= 1) { if (t < ss) red[t] += red[t+ss]; __syncthreads(); }
        const float m = red[0]*(1.0f/DIM);
        __syncthreads();
        red[t] = (u0-m)*(u0-m) + (u1-m)*(u1-m); __syncthreads();
        for (int ss = 128; ss > 0; ss >>= 1) { if (t < ss) red[t] += red[t+ss]; __syncthreads(); }
        const float rstd = rsqrtf(red[0]*(1.0f/DIM) + EPS);
        __syncthreads();

        o0 += wgr * ((u0-m)*rstd*glng[g*DIM + t]       + glnb[g*DIM + t]);
        o1 += wgr * ((u1-m)*rstd*glng[g*DIM + t + 256] + glnb[g*DIM + t + 256]);
    }
    out[n*DIM + t]       = o0;
    out[n*DIM + t + 256] = o1;
}

extern "C" void kernel_launch(void* const* d_in, const int* in_sizes, int n_in,
                              void* d_out, int out_size, void* d_ws, size_t ws_size,
                              hipStream_t stream)
{
    const float* inp  = (const float*)d_in[0];
    const float* ln_g = (const float*)d_in[1];
    const float* ln_b = (const float*)d_in[2];
    const float* wgg  = (const float*)d_in[3];
    const float* wgi  = (const float*)d_in[4];
    const float* W1   = (const float*)d_in[5];
    const float* b1   = (const float*)d_in[6];
    const float* W2   = (const float*)d_in[7];
    const float* b2   = (const float*)d_in[8];
    const float* glng = (const float*)d_in[9];
    const float* glnb = (const float*)d_in[10];
    float* out = (float*)d_out;

    char* ws = (char*)d_ws;
    float* z      = (float*)(ws + OFF_Z);
    u16*   zb     = (u16*)  (ws + OFF_ZB);
    u16*   wt     = (u16*)  (ws + OFF_WT);
    u16*   hbuf   = (u16*)  (ws + OFF_H);
    u16*   eout   = (u16*)  (ws + OFF_EO);
    int*   list   = (int*)  (ws + OFF_LIST);
    int*   slotof = (int*)  (ws + OFF_SLOT);
    int*   selg   = (int*)  (ws + OFF_SELG);
    float* gws    = (float*)(ws + OFF_GWS);
    int*   sele   = (int*)  (ws + OFF_SELE);
    float* ew     = (float*)(ws + OFF_EW);
    int*   counts = (int*)  (ws + OFF_CNT);
    int*   offs   = (int*)  (ws + OFF_OFFS);
    int*   curs   = (int*)  (ws + OFF_CUR);

    hipMemsetAsync(ws + OFF_CNT, 0, 384, stream);
    k_gate_ln<<<N_TOK, 256, 0, stream>>>(inp, ln_g, ln_b, wgg, wgi, z, zb, selg, gws, sele, ew, counts);
    k_prefix<<<1, 64, 0, stream>>>(counts, offs, curs);
    k_route<<<N_TOK/256, 256, 0, stream>>>(selg, sele, curs, offs, list, slotof);

    // W1 [32][512][2048] f32 -> wt [32][2048][512] bf16
    k_transpose_cvt<<<dim3(HID/64, DIM/64, NP), 256, 0, stream>>>(W1, wt, DIM, HID);
    k_ffn1_mfma<<<dim3(HID/128, N_TOK/128, NP), 256, 0, stream>>>(zb, wt, b1, counts, offs, list, hbuf);

    // W2 [32][2048][512] f32 -> wt [32][512][2048] bf16 (reuse buffer)
    k_transpose_cvt<<<dim3(DIM/64, HID/64, NP), 256, 0, stream>>>(W2, wt, HID, DIM);
    k_ffn2_mfma<<<dim3(DIM/128, N_TOK/128, NP*2), 256, 0, stream>>>(hbuf, wt, counts, offs, eout);

    k_final<<<N_TOK, 256, 0, stream>>>(inp, z, eout, b2, selg, gws, ew, slotof, glng, glnb, out);
}